// Round 2
// baseline (10582.137 us; speedup 1.0000x reference)
//
#include <hip/hip_runtime.h>

#define N 4096
#define NT 730
#define NTHREADS 512
#define PER_T (N / NTHREADS)   // 8
#define QLB 1e-4f
#define DT_S 3600.0f

// ---- workspace layout (4-byte element offsets) ----
#define WS_DS      0            // int[4096]
#define WS_ORDER   4096         // int[4096]
#define WS_INV     8192         // int[4096]
#define WS_LVLOFF  12288        // int[4097]
#define WS_META    16640        // int[16]
#define WS_E1      16896        // float[4096]
#define WS_E2      20992        // float[4096]
#define WS_C3      25088        // float[4096]
#define WS_C4      29184        // float[4096]
#define WS_DSP     33280        // int[4096]
#define WS_GIDX    37376        // int[4096]
// total = 41472 elements = 165,888 bytes

__global__ void k_init_ds(int* ds) {
    int j = blockIdx.x * 256 + threadIdx.x;
    if (j < N) ds[j] = N - 1;   // root sentinel; root column of adj is empty
}

// adj is row-major [i][j]; nonzero at (ds[j], j). 16M floats scanned as float4.
__global__ void k_extract(const float4* __restrict__ adj4, int* __restrict__ ds) {
    long idx = (long)blockIdx.x * 256 + threadIdx.x;
    if (idx >= (long)N * N / 4) return;
    float4 w = adj4[idx];
    long base = idx * 4;
    int row = (int)(base >> 12);      // / 4096
    int col = (int)(base & 4095);
    if (w.x != 0.0f) ds[col + 0] = row;
    if (w.y != 0.0f) ds[col + 1] = row;
    if (w.z != 0.0f) ds[col + 2] = row;
    if (w.w != 0.0f) ds[col + 3] = row;
}

// Single block: pointer-jump distance-to-root, then counting-sort nodes into
// processing-level order (descending distance => children before parents).
__global__ __launch_bounds__(1024) void k_levels(const int* __restrict__ ds,
                                                 int* __restrict__ order,
                                                 int* __restrict__ inv_perm,
                                                 int* __restrict__ lvl_off,
                                                 int* __restrict__ meta) {
    __shared__ int jA[N], dA[N], jB[N], dB[N];   // 64 KB
    __shared__ int hist[N + 1];                  // 16.4 KB
    __shared__ int base[N + 1];                  // 16.4 KB
    __shared__ int dmax_sh;
    int tid = threadIdx.x;

    for (int v = tid; v < N; v += 1024) {
        jA[v] = ds[v];
        dA[v] = (v == N - 1) ? 0 : 1;
    }
    __syncthreads();
    int *jc = jA, *dc = dA, *jn = jB, *dn = dB;
    for (int it = 0; it < 12; ++it) {            // 2^12 = 4096 >= max depth
        for (int v = tid; v < N; v += 1024) {
            int p = jc[v];
            dn[v] = dc[v] + dc[p];
            jn[v] = jc[p];
        }
        __syncthreads();
        int* t1 = jc; jc = jn; jn = t1;
        int* t2 = dc; dc = dn; dn = t2;
    }
    if (tid == 0) dmax_sh = 0;
    __syncthreads();
    int loc = 0;
    for (int v = tid; v < N; v += 1024) loc = max(loc, dc[v]);
    atomicMax(&dmax_sh, loc);
    __syncthreads();
    int Dmax = dmax_sh;

    for (int p = tid; p <= N; p += 1024) hist[p] = 0;
    __syncthreads();
    for (int v = tid; v < N; v += 1024) atomicAdd(&hist[Dmax - dc[v]], 1);
    __syncthreads();
    if (tid == 0) {
        int run = 0;
        for (int p = 0; p <= Dmax; ++p) {
            base[p] = run;
            lvl_off[p] = run;
            run += hist[p];
        }
        lvl_off[Dmax + 1] = run;   // == N
        meta[0] = Dmax + 1;        // number of processing levels P
    }
    __syncthreads();
    for (int v = tid; v < N; v += 1024) {
        int pos = atomicAdd(&base[Dmax - dc[v]], 1);
        order[pos] = v;
        inv_perm[v] = pos;
    }
}

__device__ inline void physics(int i, const float* n, const float* qs,
                               const float* ps, const float* len,
                               const float* slope, const float* width,
                               const float* xs, float& c1, float& c2,
                               float& c3, float& c4) {
    float s  = fmaxf(slope[i], 1e-4f);
    float dp = logf(width[i] / ps[i]) / logf(qs[i]);
    float v  = (1.0f / n[i]) * powf(dp, 2.0f / 3.0f) * sqrtf(s);
    float c  = fminf(fmaxf(v, 0.3f), 15.0f) * (5.0f / 3.0f);
    float k  = len[i] / c;
    float x  = xs[i];
    float denom = 2.0f * k * (1.0f - x) + DT_S;
    c1 = (DT_S - 2.0f * k * x) / denom;
    c2 = (DT_S + 2.0f * k * x) / denom;
    c3 = (2.0f * k * (1.0f - x) - DT_S) / denom;
    c4 = 2.0f * DT_S / denom;
}

__global__ void k_coeffs(const int* __restrict__ ds, const int* __restrict__ order,
                         const int* __restrict__ inv_perm,
                         const float* n, const float* qs, const float* ps,
                         const float* len, const float* slope, const float* width,
                         const float* xs,
                         float* __restrict__ e1, float* __restrict__ e2,
                         float* __restrict__ c3P, float* __restrict__ c4P,
                         int* __restrict__ dsP, int* __restrict__ gidx) {
    int v = blockIdx.x * 256 + threadIdx.x;
    if (v >= N) return;
    int j = order[v];
    float a1, a2, a3, a4;
    physics(j, n, qs, ps, len, slope, width, xs, a1, a2, a3, a4);
    c3P[v] = a3;
    c4P[v] = a4;
    gidx[v] = j;
    if (j == N - 1) {                 // root: no downstream
        dsP[v] = v;
        e1[v] = 0.0f;
        e2[v] = 0.0f;
    } else {
        int d = ds[j];
        float b1, b2, b3, b4;
        physics(d, n, qs, ps, len, slope, width, xs, b1, b2, b3, b4);
        dsP[v] = inv_perm[d];
        e1[v] = b1;                   // c1[parent]
        e2[v] = b2;                   // c2[parent]
    }
}

// Persistent single-workgroup routing kernel. All indices are permuted
// (level-sorted) space; root == permuted index N-1 (the only distance-0 node).
__global__ __launch_bounds__(NTHREADS) void k_route(
    const float* __restrict__ qp, const float* __restrict__ e1g,
    const float* __restrict__ e2g, const float* __restrict__ c3g,
    const float* __restrict__ c4g, const int* __restrict__ dsPg,
    const int* __restrict__ gidxg, const int* __restrict__ lvl_offg,
    const int* __restrict__ meta, float* __restrict__ out) {
    __shared__ float S[N];       // per-step accumulator: b then x
    __shared__ float q[N];       // state (clipped)
    __shared__ float e1[N];      // c1[parent], for dynamic-v level loop
    __shared__ int dsP[N];
    __shared__ int off[N + 1];
    __shared__ int Psh;
    int tid = threadIdx.x;

    if (tid == 0) Psh = meta[0];
    for (int v = tid; v < N; v += NTHREADS) {
        e1[v] = e1g[v];
        dsP[v] = dsPg[v];
    }
    __syncthreads();
    int P = Psh;
    for (int p = tid; p <= P; p += NTHREADS) off[p] = lvl_offg[p];

    // own-node constants in registers (static ownership v = tid + 512*r)
    int g[PER_T], dsp_own[PER_T];
    float e2r[PER_T], c3r[PER_T], c4r[PER_T], qcur[PER_T], qnext[PER_T];
#pragma unroll
    for (int r = 0; r < PER_T; ++r) {
        int v = tid + NTHREADS * r;
        g[r] = gidxg[v];
        e2r[r] = e2g[v];
        c3r[r] = c3g[v];
        c4r[r] = c4g[v];
        dsp_own[r] = dsPg[v];
        float q0 = qp[g[r]];     // row 0, UNclipped initial state
        q[v] = q0;
        qcur[r] = q0;            // row 0 is also step 1's lateral-inflow row
    }
    if (tid == 0) out[0] = fmaxf(qp[N - 1], QLB);
    __syncthreads();

    for (int t = 1; t < NT; ++t) {
        // Phase A: S[v] = c3*q_old + c4*clip(qp_row)
#pragma unroll
        for (int r = 0; r < PER_T; ++r) {
            int v = tid + NTHREADS * r;
            S[v] = c3r[r] * q[v] + c4r[r] * fmaxf(qcur[r], QLB);
        }
        __syncthreads();
        // Phase B: upstream-inflow scatter  S[parent] += c2[parent]*q_old[child]
#pragma unroll
        for (int r = 0; r < PER_T; ++r) {
            int v = tid + NTHREADS * r;
            if (v != N - 1) atomicAdd(&S[dsp_own[r]], e2r[r] * q[v]);
        }
        // prefetch next q_prime row (latency hidden under phase C)
        if (t < NT - 1) {
            const float* row = qp + (size_t)t * N;
#pragma unroll
            for (int r = 0; r < PER_T; ++r) qnext[r] = row[g[r]];
        }
        __syncthreads();
        // Phase C: level-ordered solve  x[v] = S[v];  S[parent] += c1[parent]*x
        for (int p = 0; p < P; ++p) {
            int s = off[p], e = off[p + 1];
            for (int v = s + tid; v < e; v += NTHREADS) {
                float x = S[v];
                if (v != N - 1) atomicAdd(&S[dsP[v]], e1[v] * x);
                q[v] = fmaxf(x, QLB);
            }
            __syncthreads();
        }
        if (tid == 0) out[t] = q[N - 1];   // gage = root
#pragma unroll
        for (int r = 0; r < PER_T; ++r) qcur[r] = qnext[r];
    }
}

extern "C" void kernel_launch(void* const* d_in, const int* in_sizes, int n_in,
                              void* d_out, int out_size, void* d_ws, size_t ws_size,
                              hipStream_t stream) {
    const float* qp    = (const float*)d_in[0];   // [730,4096]
    const float* n     = (const float*)d_in[1];
    const float* qs    = (const float*)d_in[2];
    const float* ps    = (const float*)d_in[3];
    const float* len   = (const float*)d_in[4];
    const float* slope = (const float*)d_in[5];
    const float* width = (const float*)d_in[6];
    const float* xs    = (const float*)d_in[7];
    const float* adj   = (const float*)d_in[8];   // [4096,4096]
    float* out = (float*)d_out;

    int*   W     = (int*)d_ws;
    int*   ds    = W + WS_DS;
    int*   order = W + WS_ORDER;
    int*   inv   = W + WS_INV;
    int*   lvlo  = W + WS_LVLOFF;
    int*   meta  = W + WS_META;
    float* e1    = (float*)(W + WS_E1);
    float* e2    = (float*)(W + WS_E2);
    float* c3P   = (float*)(W + WS_C3);
    float* c4P   = (float*)(W + WS_C4);
    int*   dsP   = W + WS_DSP;
    int*   gidx  = W + WS_GIDX;

    k_init_ds<<<(N + 255) / 256, 256, 0, stream>>>(ds);
    k_extract<<<(N * N / 4 + 255) / 256, 256, 0, stream>>>((const float4*)adj, ds);
    k_levels<<<1, 1024, 0, stream>>>(ds, order, inv, lvlo, meta);
    k_coeffs<<<(N + 255) / 256, 256, 0, stream>>>(ds, order, inv, n, qs, ps, len,
                                                  slope, width, xs,
                                                  e1, e2, c3P, c4P, dsP, gidx);
    k_route<<<1, NTHREADS, 0, stream>>>(qp, e1, e2, c3P, c4P, dsP, gidx,
                                        lvlo, meta, out);
}

// Round 3
// 10553.806 us; speedup vs baseline: 1.0027x; 1.0027x over previous
//
#include <hip/hip_runtime.h>

#define N 4096
#define NT 730
#define NTH 512
#define PER_T (N / NTH)        // 8
#define E_REG 80               // register-resident W entries per thread
#define ECAP (NTH * E_REG)     // 40960
#define CAPTOT 49152           // total entry storage in workspace
#define QLB 1e-4f
#define DT_S 3600.0f
#define NEG_INF (-3.0e38f)

// ---- workspace layout (4-byte element offsets) ----
#define WS_DS     0            // int[4096]
#define WS_CNT    4096         // int[4096]   W row counts (atomic)
#define WS_RS     8192         // int[4097]   row_start (exclusive scan)
#define WS_CUR    12289        // int[4096]   fill cursor (copy of row_start)
#define WS_CCNT   16385        // int[4096]   children counts
#define WS_COFF   20481        // int[4097]   children CSR offsets
#define WS_CCUR   24578        // int[4096]   children fill cursor
#define WS_META   28674        // int[16]     meta[1] = nnz
#define WS_C1     28690        // float[4096]
#define WS_C2     32786        // float[4096]
#define WS_C3     36882        // float[4096]
#define WS_C4     40978        // float[4096]
#define WS_CLIST  45074        // int[4096]   children CSR list
#define WS_EPACK  49170        // int[49152]  (row<<16)|col, sorted by row
#define WS_EW     98322        // float[49152] path-product weights
// end = 147474 elements = 589,896 bytes

__global__ void k_init(int* ds, int* cnt, int* ccnt) {
    int j = blockIdx.x * 256 + threadIdx.x;
    if (j < N) { ds[j] = N - 1; cnt[j] = 0; ccnt[j] = 0; }
}

// adj row-major [i][j]; nonzero at (ds[j], j). 16M floats scanned as float4.
__global__ void k_extract(const float4* __restrict__ adj4, int* __restrict__ ds) {
    long idx = (long)blockIdx.x * 256 + threadIdx.x;
    if (idx >= (long)N * N / 4) return;
    float4 w = adj4[idx];
    long base = idx * 4;
    int row = (int)(base >> 12);
    int col = (int)(base & 4095);
    if (w.x != 0.0f) ds[col + 0] = row;
    if (w.y != 0.0f) ds[col + 1] = row;
    if (w.z != 0.0f) ds[col + 2] = row;
    if (w.w != 0.0f) ds[col + 3] = row;
}

__global__ void k_coeffs(const float* n, const float* qs, const float* ps,
                         const float* len, const float* slope, const float* width,
                         const float* xs, float* __restrict__ c1, float* __restrict__ c2,
                         float* __restrict__ c3, float* __restrict__ c4) {
    int i = blockIdx.x * 256 + threadIdx.x;
    if (i >= N) return;
    float s  = fmaxf(slope[i], 1e-4f);
    float dp = logf(width[i] / ps[i]) / logf(qs[i]);
    float v  = (1.0f / n[i]) * powf(dp, 2.0f / 3.0f) * sqrtf(s);
    float c  = fminf(fmaxf(v, 0.3f), 15.0f) * (5.0f / 3.0f);
    float k  = len[i] / c;
    float x  = xs[i];
    float denom = 2.0f * k * (1.0f - x) + DT_S;
    c1[i] = (DT_S - 2.0f * k * x) / denom;
    c2[i] = (DT_S + 2.0f * k * x) / denom;
    c3[i] = (2.0f * k * (1.0f - x) - DT_S) / denom;
    c4[i] = 2.0f * DT_S / denom;
}

// Per node u: walk to root, counting one W entry per ancestor; also in-degree.
__global__ void k_count(const int* __restrict__ ds, int* __restrict__ cnt,
                        int* __restrict__ ccnt) {
    int u = blockIdx.x * 256 + threadIdx.x;
    if (u >= N || u == N - 1) return;
    int p = ds[u];
    atomicAdd(&ccnt[p], 1);
    while (true) {
        atomicAdd(&cnt[p], 1);
        if (p == N - 1) break;
        p = ds[p];
    }
}

// Single block: exclusive scans (4096) for W-rows CSR and children CSR.
__global__ __launch_bounds__(1024) void k_scan(const int* cnt, int* rs, int* cur,
                                               const int* ccnt, int* coff, int* ccur,
                                               int* meta) {
    __shared__ int buf[1024];
    int tid = threadIdx.x;
    for (int pass = 0; pass < 2; ++pass) {
        const int* src = pass ? ccnt : cnt;
        int* o1 = pass ? coff : rs;
        int* o2 = pass ? ccur : cur;
        int a0 = src[tid * 4 + 0], a1 = src[tid * 4 + 1];
        int a2 = src[tid * 4 + 2], a3 = src[tid * 4 + 3];
        int s1 = a0, s2 = a0 + a1, s3 = a0 + a1 + a2, tot = s3 + a3;
        buf[tid] = tot;
        __syncthreads();
        for (int off = 1; off < 1024; off <<= 1) {
            int add = (tid >= off) ? buf[tid - off] : 0;
            __syncthreads();
            buf[tid] += add;
            __syncthreads();
        }
        int base = buf[tid] - tot;   // exclusive prefix
        o1[tid * 4 + 0] = base;      o2[tid * 4 + 0] = base;
        o1[tid * 4 + 1] = base + s1; o2[tid * 4 + 1] = base + s1;
        o1[tid * 4 + 2] = base + s2; o2[tid * 4 + 2] = base + s2;
        o1[tid * 4 + 3] = base + s3; o2[tid * 4 + 3] = base + s3;
        if (tid == 1023) { o1[N] = buf[1023]; if (!pass) meta[1] = buf[1023]; }
        __syncthreads();
    }
}

// Per node u: walk to root, emitting W entries (row=ancestor, col=u,
// w = f64 running product of c1[ancestors]); CSR placement => row-sorted.
__global__ void k_fill(const int* __restrict__ ds, const float* __restrict__ c1,
                       int* __restrict__ cur, int* __restrict__ ccur,
                       int* __restrict__ clist, int* __restrict__ epack,
                       float* __restrict__ ew) {
    int u = blockIdx.x * 256 + threadIdx.x;
    if (u >= N || u == N - 1) return;
    int p = ds[u];
    int cp = atomicAdd(&ccur[p], 1);
    clist[cp] = u;
    double w = 1.0;
    while (true) {
        w *= (double)c1[p];
        int pos = atomicAdd(&cur[p], 1);
        if (pos < CAPTOT) { epack[pos] = (p << 16) | u; ew[pos] = (float)w; }
        if (p == N - 1) break;
        p = ds[p];
    }
}

// Persistent single-workgroup routing. Per step: 2 barriers.
//   Phase A: b = c3*q + c4*clip(ql) + c2*sum_child q   (q = clip(Bp+Zp))
//   Phase B: x = W b via register-resident segmented SpMV; x[v] = B[v]+Z[v].
__global__ __launch_bounds__(NTH) void k_route(
    const float* __restrict__ qp, const float* __restrict__ c2g,
    const float* __restrict__ c3g, const float* __restrict__ c4g,
    const int* __restrict__ coff, const int* __restrict__ clist,
    const int* __restrict__ epack, const float* __restrict__ ew,
    const int* __restrict__ meta, float* __restrict__ out) {
    __shared__ float B[2][N];
    __shared__ float Z[2][N];
    __shared__ int CL[N];
    int tid = threadIdx.x;
    int nnz = meta[1];

    // load register-resident W entries (pad tail with weight-0 root entries)
    unsigned int pk[E_REG];
    float wv[E_REG];
#pragma unroll
    for (int e = 0; e < E_REG; ++e) {
        int i = tid * E_REG + e;
        bool ok = (i < nnz) && (i < CAPTOT);
        pk[e] = ok ? (unsigned int)epack[i]
                   : (((unsigned int)(N - 1) << 16) | (unsigned int)(N - 1));
        wv[e] = ok ? ew[i] : 0.0f;
    }
    // own-node constants (static ownership v = tid + 512*r)
    float c2r[PER_T], c3r[PER_T], c4r[PER_T], qc[PER_T], qn[PER_T];
    int cb[PER_T], ce[PER_T];
#pragma unroll
    for (int r = 0; r < PER_T; ++r) {
        int v = tid + NTH * r;
        c2r[r] = c2g[v]; c3r[r] = c3g[v]; c4r[r] = c4g[v];
        cb[r] = coff[v]; ce[r] = coff[v + 1];
        float q0 = qp[v];            // row 0: raw initial state
        B[0][v] = q0; Z[0][v] = 0.0f;
        qc[r] = q0;                  // row 0 is also step 1's lateral inflow
    }
    for (int i = tid; i < N; i += NTH) CL[i] = clist[i];
    if (tid == 0) out[0] = fmaxf(qp[N - 1], QLB);
    __syncthreads();

    for (int t = 1; t < NT; ++t) {
        int s = t & 1, sp = s ^ 1;
        float* Bs = B[s];
        float* Zs = Z[s];
        const float* Bp = B[sp];
        const float* Zp = Z[sp];
        float lbp = (t == 1) ? NEG_INF : QLB;   // step-1 prev state is UNclipped

        // Phase A
#pragma unroll
        for (int r = 0; r < PER_T; ++r) {
            int v = tid + NTH * r;
            float xp = fmaxf(Bp[v] + Zp[v], lbp);
            float ssum = 0.0f;
            for (int k = cb[r]; k < ce[r]; ++k) {
                int c = CL[k];
                ssum += fmaxf(Bp[c] + Zp[c], lbp);
            }
            Bs[v] = c3r[r] * xp + c4r[r] * fmaxf(qc[r], QLB) + c2r[r] * ssum;
            Zs[v] = 0.0f;
        }
        // prefetch next q_prime row (hidden under Phase B)
        if (t < NT - 1) {
            const float* row = qp + (size_t)t * N;
#pragma unroll
            for (int r = 0; r < PER_T; ++r) qn[r] = row[tid + NTH * r];
        }
        __syncthreads();

        // Phase B: segmented SpMV over row-sorted register entries
        {
            int curRow = (int)(pk[0] >> 16);
            double acc = 0.0;
#pragma unroll
            for (int e = 0; e < E_REG; ++e) {
                unsigned int p = pk[e];
                int rw = (int)(p >> 16);
                int cl = (int)(p & 0xFFFFu);
                float prod = wv[e] * Bs[cl];
                if (rw != curRow) {
                    atomicAdd(&Zs[curRow], (float)acc);
                    acc = 0.0;
                    curRow = rw;
                }
                acc += (double)prod;
            }
            atomicAdd(&Zs[curRow], (float)acc);
            // overflow entries (only if nnz > ECAP): from global/L2
            for (int i = ECAP + tid; i < nnz && i < CAPTOT; i += NTH) {
                unsigned int p = (unsigned int)epack[i];
                atomicAdd(&Zs[p >> 16], ew[i] * Bs[p & 0xFFFFu]);
            }
        }
        __syncthreads();
        if (tid == 0) out[t] = fmaxf(Bs[N - 1] + Zs[N - 1], QLB);
#pragma unroll
        for (int r = 0; r < PER_T; ++r) qc[r] = qn[r];
    }
}

extern "C" void kernel_launch(void* const* d_in, const int* in_sizes, int n_in,
                              void* d_out, int out_size, void* d_ws, size_t ws_size,
                              hipStream_t stream) {
    const float* qp    = (const float*)d_in[0];   // [730,4096]
    const float* n     = (const float*)d_in[1];
    const float* qs    = (const float*)d_in[2];
    const float* ps    = (const float*)d_in[3];
    const float* len   = (const float*)d_in[4];
    const float* slope = (const float*)d_in[5];
    const float* width = (const float*)d_in[6];
    const float* xs    = (const float*)d_in[7];
    const float* adj   = (const float*)d_in[8];   // [4096,4096]
    float* out = (float*)d_out;

    int*   W     = (int*)d_ws;
    int*   ds    = W + WS_DS;
    int*   cnt   = W + WS_CNT;
    int*   rs    = W + WS_RS;
    int*   cur   = W + WS_CUR;
    int*   ccnt  = W + WS_CCNT;
    int*   coff  = W + WS_COFF;
    int*   ccur  = W + WS_CCUR;
    int*   meta  = W + WS_META;
    float* c1    = (float*)(W + WS_C1);
    float* c2    = (float*)(W + WS_C2);
    float* c3    = (float*)(W + WS_C3);
    float* c4    = (float*)(W + WS_C4);
    int*   clist = W + WS_CLIST;
    int*   epack = W + WS_EPACK;
    float* ew    = (float*)(W + WS_EW);

    k_init<<<(N + 255) / 256, 256, 0, stream>>>(ds, cnt, ccnt);
    k_extract<<<(N * N / 4 + 255) / 256, 256, 0, stream>>>((const float4*)adj, ds);
    k_coeffs<<<(N + 255) / 256, 256, 0, stream>>>(n, qs, ps, len, slope, width, xs,
                                                  c1, c2, c3, c4);
    k_count<<<(N + 255) / 256, 256, 0, stream>>>(ds, cnt, ccnt);
    k_scan<<<1, 1024, 0, stream>>>(cnt, rs, cur, ccnt, coff, ccur, meta);
    k_fill<<<(N + 255) / 256, 256, 0, stream>>>(ds, c1, cur, ccur, clist, epack, ew);
    k_route<<<1, NTH, 0, stream>>>(qp, c2, c3, c4, coff, clist, epack, ew, meta, out);
}